// Round 1
// 77.213 us; speedup vs baseline: 1.0798x; 1.0798x over previous
//
#include <hip/hip_runtime.h>
#include <stdint.h>

#define BN       16384
#define NTILES   256     // BN/64
#define NB       64      // norm buckets
#define KOUT     16
#define MARGIN   0.01f   // certified slack >> max fp32 eval error (~4e-5)

typedef float v2f __attribute__((ext_vector_type(2)));
union F4 { float4 f4; v2f p[2]; float f[4]; };

// ---- workspace layout (bytes) ----
#define WS_TAB    0                         // float4[BN]    262144
#define WS_IDX    (WS_TAB + BN * 16)        // u16[BN]        32768 (slot kept 64KB)
#define WS_BND    (WS_IDX + BN * 4)         // float2[NTILES]  2048
#define WS_HIST   (WS_BND + NTILES * 8)     // u32[64][NB]    16384
#define WS_HMAX   (WS_HIST + 64 * NB * 4)   // u32[64][NB]    16384

// sortable key of float bits (ascending uint == ascending float)
__device__ __forceinline__ unsigned key_u(unsigned u) {
    return u ^ ((unsigned)((int)u >> 31) | 0x80000000u);
}
__device__ __forceinline__ unsigned wshr1(unsigned v, unsigned oldv) {
    return (unsigned)__builtin_amdgcn_update_dpp((int)oldv, (int)v, 0x138 /*WAVE_SHR:1*/,
                                                 0xF, 0xF, false);
}
#define RL16(T) __uint_as_float((unsigned)__builtin_amdgcn_readlane(__float_as_int(T), 16))

// exact np-order squared norm: (x^2 + y^2) + z^2
__device__ __forceinline__ float sq_of(float gx, float gy, float gz) {
    return __fadd_rn(__fadd_rn(__fmul_rn(gx, gx), __fmul_rn(gy, gy)), __fmul_rn(gz, gz));
}
__device__ __forceinline__ int bucket_of(float sq) {
    const float rho = __fsqrt_rn(sq);
    int b = (int)(64.0f * (1.0f - rho * 0.2f));  // edges rho_b = 5*(1-b/64)
    return (b < 0) ? 0 : ((b > 63) ? 63 : b);
}

// Lexicographic (pair asc, idx asc) sorted insert -> scan-order independent.
#define DRAIN(m, p, jvec, T, J)                                                     \
    while (m) {                                                                     \
        const int b_ = (int)__builtin_ctzll(m);                                     \
        m &= m - 1;                                                                 \
        const float pc_ = __uint_as_float(                                          \
            (unsigned)__builtin_amdgcn_readlane(__float_as_int(p), b_));            \
        const unsigned jc_ = (unsigned)__builtin_amdgcn_readlane((int)(jvec), b_);  \
        const float Tup_ =                                                          \
            __uint_as_float(wshr1(__float_as_uint(T), 0xFF800000u /*-inf*/));       \
        const unsigned Jup_ = wshr1((J), 0u);                                       \
        const bool lt_ = (pc_ < Tup_) || ((pc_ == Tup_) && (jc_ < Jup_));           \
        const float Tn_ = lt_ ? Tup_ : pc_;                                         \
        const unsigned Jn_ = lt_ ? Jup_ : jc_;                                      \
        const bool sel_ = (pc_ < (T)) || ((pc_ == (T)) && (jc_ < (J)));             \
        (T) = sel_ ? Tn_ : (T);                                                     \
        (J) = sel_ ? Jn_ : (J);                                                     \
    }

// d2 = ((2*dot + nsq_q) + nsq_j) packed for 2 queries, bitwise == reference chain.
#define EVALC(c, d2)                                                                \
    asm("v_pk_mul_f32 %0, %1, %2 op_sel:[0,0] op_sel_hi:[0,1]"                      \
        : "=v"(d2) : "v"((c).p[0]), "v"(c0A));                                      \
    asm("v_pk_fma_f32 %0, %1, %2, %0 op_sel:[1,0,0] op_sel_hi:[1,1,1]"              \
        : "+v"(d2) : "v"((c).p[0]), "v"(c1A));                                      \
    asm("v_pk_fma_f32 %0, %1, %2, %0 op_sel:[0,0,0] op_sel_hi:[0,1,1]"              \
        : "+v"(d2) : "v"((c).p[1]), "v"(c2A));                                      \
    asm("v_pk_add_f32 %0, %0, %1" : "+v"(d2) : "v"(nsq01));                         \
    asm("v_pk_add_f32 %0, %0, %1 op_sel:[0,1] op_sel_hi:[1,1]"                      \
        : "+v"(d2) : "v"((c).p[1]));

#define TILE_AT(t)                                                                  \
    F4 c; c.f4 = tab[(t) * 64 + lane];                                              \
    const unsigned jvec = (unsigned)idx16[(t) * 64 + lane];                         \
    v2f d2; EVALC(c, d2)

#define PROCESS_LOADED()                                                            \
    do {                                                                            \
        uint64_t m0 = __ballot(d2[0] <= fF0);                                       \
        uint64_t m1 = __ballot(d2[1] <= fF1);                                       \
        if (m0 | m1) {                                                              \
            const float p0v = d2[0], p1v = d2[1];                                   \
            DRAIN(m0, p0v, jvec, T0, J0)                                            \
            DRAIN(m1, p1v, jvec, T1, J1)                                            \
            fF0 = RL16(T0); thr0 = __fsub_rn(-fF0, MARGIN);                         \
            fF1 = RL16(T1); thr1 = __fsub_rn(-fF1, MARGIN);                         \
        }                                                                           \
    } while (0)

// certificate test for the 64 tiles held in register pair bd (lane l = tile l of chunk)
// identical FP chain to the original per-tile test; u(t) weakly nonincreasing in t,
// so certified tiles form a suffix and ctz(ballot) is the exact first-certified tile.
#define CERTM(bd)                                                                    \
    __ballot((__builtin_fmaf(twor0, (bd)[1], __fadd_rn(sq0, (bd)[0])) < thr0) &&     \
             (__builtin_fmaf(twor1, (bd)[1], __fadd_rn(sq1, (bd)[0])) < thr1))

#define COMPUTE_TSTAR()                                                              \
    do {                                                                             \
        uint64_t mm;                                                                 \
        if ((mm = CERTM(bdA)))        ts = (int)__builtin_ctzll(mm);                 \
        else if ((mm = CERTM(bdB)))   ts = 64  + (int)__builtin_ctzll(mm);           \
        else if ((mm = CERTM(bdC)))   ts = 128 + (int)__builtin_ctzll(mm);           \
        else if ((mm = CERTM(bdD)))   ts = 192 + (int)__builtin_ctzll(mm);           \
        else                          ts = NTILES;                                   \
    } while (0)

// Wave-parallel exact sort of 64 (p, j) pairs by (p asc, j asc) — R11 verbatim.
__device__ __forceinline__ void presort64(float p, unsigned j, int lane, double* sw,
                                          float& T, unsigned& J) {
    const double dm = (double)key_u(__float_as_uint(p)) * 16384.0 + (double)j;
    sw[lane] = dm;
    unsigned rank = 0;
    const char* sb = (const char*)sw;
    unsigned off = (unsigned)lane * 8u;
#pragma unroll 7
    for (int s = 1; s < 64; ++s) {
        off = (off + 8u) & 511u;
        const double dn = *(const double*)(sb + off);
        rank += (dn < dm) ? 1u : 0u;
    }
    sw[rank] = __longlong_as_double(
        (long long)(((unsigned long long)j << 32) | __float_as_uint(p)));
    const unsigned long long v = (unsigned long long)__double_as_longlong(sw[lane]);
    T = __uint_as_float((unsigned)(v & 0xFFFFFFFFull));
    J = (unsigned)(v >> 32);
}

// ---- prep 1: per-block histogram + per-bucket max norm (64 blocks) ----
__global__ __launch_bounds__(256) void k_hist(const float* __restrict__ x,
                                              unsigned* __restrict__ hist,
                                              unsigned* __restrict__ hmax) {
    __shared__ unsigned h[NB], m[NB];
    const int tid = threadIdx.x;
    if (tid < NB) { h[tid] = 0u; m[tid] = 0u; }
    __syncthreads();
    const int i = blockIdx.x * 256 + tid;
    const float sq = sq_of(x[3 * i], x[3 * i + 1], x[3 * i + 2]);
    const int b = bucket_of(sq);
    atomicAdd(&h[b], 1u);
    atomicMax(&m[b], __float_as_uint(sq));  // sq>0: float bits monotone
    __syncthreads();
    if (tid < NB) {
        hist[blockIdx.x * NB + tid] = h[tid];
        hmax[blockIdx.x * NB + tid] = m[tid];
    }
}

// ---- prep 2 (fused mid+scatter, 64 blocks): each block redundantly reduces the
// 64x64 histogram, computes global bases + its own column cursor bases, scatters
// its 256 points; block 0 additionally writes the per-tile bounds. ----
__global__ __launch_bounds__(256) void k_prep(const float* __restrict__ x,
                                              const unsigned* __restrict__ hist,
                                              const unsigned* __restrict__ hmax,
                                              float4* __restrict__ tab,
                                              unsigned short* __restrict__ idx16,
                                              float2* __restrict__ bnd) {
    __shared__ unsigned colbase[NB], cur[NB], basev[NB + 1], mxv[NB], sfxs[NB];
    const int tid = threadIdx.x;
    const int blk = blockIdx.x;
    if (tid < NB) {
        unsigned tot = 0u, part = 0u, mx = 0u;
#pragma unroll 8
        for (int g = 0; g < 64; ++g) {
            const unsigned h = hist[g * NB + tid];
            tot += h;
            part += (g < blk) ? h : 0u;
            const unsigned w = hmax[g * NB + tid];
            mx = (w > mx) ? w : mx;
        }
        // exclusive scan of tot across wave 0 (tid == lane)
        unsigned v = tot;
#pragma unroll
        for (int s = 1; s < 64; s <<= 1) {
            const unsigned n = (unsigned)__shfl_up((int)v, (unsigned)s, 64);
            v += (tid >= s) ? n : 0u;
        }
        basev[tid] = v - tot;  // exclusive prefix
        if (tid == NB - 1) basev[NB] = v;
        colbase[tid] = (v - tot) + part;
        cur[tid] = 0u;
        mxv[tid] = mx;
    }
    __syncthreads();
    // scatter this block's 256 points (layout within a segment is order-free;
    // final output is scan-order independent via lexicographic DRAIN)
    const int i = blk * 256 + tid;
    const float gx = x[3 * i], gy = x[3 * i + 1], gz = x[3 * i + 2];
    const float sq = sq_of(gx, gy, gz);
    const int b = bucket_of(sq);
    const unsigned r = atomicAdd(&cur[b], 1u);
    const unsigned pos = colbase[b] + r;
    tab[pos] = make_float4(gx, gy, gz, -sq);
    idx16[pos] = (unsigned short)i;

    if (blk == 0) {  // block-uniform branch: syncthreads inside is legal
        if (tid == 0) {
            unsigned M = 0u;
            for (int b2 = NB - 1; b2 >= 0; --b2) {
                const unsigned w = mxv[b2];
                M = (w > M) ? w : M;
                sfxs[b2] = M;
            }
        }
        __syncthreads();
        // per-tile bound: bucket containing position 64*tid, then suffix bucket max
        const unsigned posb = (unsigned)tid * 64u;
        int bb = 0;
        for (int t2 = 0; t2 < NB; ++t2)
            if (basev[t2] <= posb && posb < basev[t2 + 1]) bb = t2;
        const float B = __uint_as_float(sfxs[bb]);
        const float sqB_up = __uint_as_float(__float_as_uint(__fsqrt_rn(B)) + 2u);
        bnd[tid] = make_float2(B, sqB_up);
    }
}

// ---- main kernel: norm-paired queries, register-resident bounds, precomputed t* ----
__global__ __launch_bounds__(256) void knn_far_kernel(
    const float4* __restrict__ tab, const unsigned short* __restrict__ idx16,
    const float2* __restrict__ bnd, float* __restrict__ out_d, float* __restrict__ out_i) {
    __shared__ double swall[4 * 64];
    const int tid  = threadIdx.x;
    const int lane = tid & 63;
    const int wid  = tid >> 6;
    double* sw = swall + wid * 64;
    // paired queries = adjacent positions in the norm-sorted table (correlated exit tiles)
    const int p0 = (blockIdx.x * 4 + wid) * 2;
    const int p1 = p0 + 1;

    F4 qa; qa.f4 = tab[p0];
    F4 qb; qb.f4 = tab[p1];
    const unsigned q0 = (unsigned)idx16[p0];
    const unsigned q1 = (unsigned)idx16[p1];
    const float sq0 = -qa.f[3], sq1 = -qb.f[3];        // tab.w = -sq (exact)
    const v2f nsq01 = {qa.f[3], qb.f[3]};              // {-sq0, -sq1}
    const v2f c0A = {2.0f * qa.f[0], 2.0f * qb.f[0]};
    const v2f c1A = {2.0f * qa.f[1], 2.0f * qb.f[1]};
    const v2f c2A = {2.0f * qa.f[2], 2.0f * qb.f[2]};
    // upper-bounded 2*|q| for the certificate
    const float twor0 = 2.0f * __uint_as_float(__float_as_uint(__fsqrt_rn(sq0)) + 2u);
    const float twor1 = 2.0f * __uint_as_float(__float_as_uint(__fsqrt_rn(sq1)) + 2u);

    // all 256 tile bounds live in 4 register pairs: lane l holds tiles l, 64+l, 128+l, 192+l
    const v2f* bndv = (const v2f*)bnd;
    const v2f bdA = bndv[lane];
    const v2f bdB = bndv[64 + lane];
    const v2f bdC = bndv[128 + lane];
    const v2f bdD = bndv[192 + lane];

    float T0, T1; unsigned J0, J1;
    float fF0, fF1, thr0, thr1;

    {   // tile 0: seed via wave-parallel presort (no insert flood)
        TILE_AT(0)
        presort64(d2[0], jvec, lane, sw, T0, J0);
        presort64(d2[1], jvec, lane, sw, T1, J1);
        fF0 = RL16(T0); thr0 = __fsub_rn(-fF0, MARGIN);
        fF1 = RL16(T1); thr1 = __fsub_rn(-fF1, MARGIN);
    }
#pragma unroll
    for (int t = 1; t < 4; ++t) {  // rest of the seed region (top-256 norms)
        TILE_AT(t)
        PROCESS_LOADED();
    }

    int ts;
    COMPUTE_TSTAR();               // first tile certified for BOTH queries (exact, monotone)
    for (int t = 4; t < ts; ++t) {
        TILE_AT(t)
        uint64_t m0 = __ballot(d2[0] <= fF0);
        uint64_t m1 = __ballot(d2[1] <= fF1);
        if (m0 | m1) {
            const float p0v = d2[0], p1v = d2[1];
            DRAIN(m0, p0v, jvec, T0, J0)
            DRAIN(m1, p1v, jvec, T1, J1)
            fF0 = RL16(T0); thr0 = __fsub_rn(-fF0, MARGIN);
            fF1 = RL16(T1); thr1 = __fsub_rn(-fF1, MARGIN);
            COMPUTE_TSTAR();       // threshold only improves -> ts only shrinks
        }
    }

    if (lane >= 1 && lane <= KOUT) {  // ranks 1..16 (rank 0 dropped by reference)
        const int r = lane - 1;
        out_d[q0 * KOUT + r] = T0;
        out_i[q0 * KOUT + r] = (float)J0;
        out_d[q1 * KOUT + r] = T1;
        out_i[q1 * KOUT + r] = (float)J1;
    }
}

extern "C" void kernel_launch(void* const* d_in, const int* in_sizes, int n_in,
                              void* d_out, int out_size, void* d_ws, size_t ws_size,
                              hipStream_t stream) {
    const float* x = (const float*)d_in[0];
    char* ws = (char*)d_ws;
    float4*         tab   = (float4*)(ws + WS_TAB);
    unsigned short* idx16 = (unsigned short*)(ws + WS_IDX);
    float2*         bnd   = (float2*)(ws + WS_BND);
    unsigned*       hist  = (unsigned*)(ws + WS_HIST);
    unsigned*       hmax  = (unsigned*)(ws + WS_HMAX);
    float* out_d = (float*)d_out;
    float* out_i = out_d + (size_t)BN * KOUT;

    hipLaunchKernelGGL(k_hist, dim3(64), dim3(256), 0, stream, x, hist, hmax);
    hipLaunchKernelGGL(k_prep, dim3(64), dim3(256), 0, stream, x, hist, hmax,
                       tab, idx16, bnd);
    hipLaunchKernelGGL(knn_far_kernel, dim3(BN / 8), dim3(256), 0, stream,
                       tab, idx16, bnd, out_d, out_i);
}